// Round 4
// baseline (83.210 us; speedup 1.0000x reference)
//
#include <hip/hip_runtime.h>

// x     [B=32, I=64, K=8192]        f32
// U_in  [I=64, R=8,  K=8192, H=4]   f32  -> float4 per (i,r,k)
// M     [R=8,  S=8,  K=8192, H=4]   f32
// U_out [O=64, S=8,  K=8192, H=4]   f32
// out   [B=32, O=64, K=8192]        f32
//
// Block = 16 kk x 16 bslot (256 thr), 2 b per thread. Grid = 512 (1 block/k-tile).
// 17 weight chunks ([64 rows][16 k][4 h] = 16 KB each) flow through a QUAD-
// buffered LDS ring staged by global_load_lds, issued 2 phases ahead.
// ONE barrier per phase (reuse distance 4 makes the trailing barrier redundant),
// counted vmcnt (24 in x-phases, 8 after; never 0 mid-loop).

static constexpr int IN_CH  = 64;
static constexpr int OUT_CH = 64;
static constexpr int RANK   = 8;
static constexpr int MODES  = 8192;
static constexpr int KT     = 16;            // k per block
static constexpr int CROWS  = 64;            // rows per chunk
static constexpr int CF4    = CROWS * KT;    // 1024 float4 = 16 KB per chunk

typedef const __attribute__((address_space(1))) void* gas_t;
typedef __attribute__((address_space(3))) void* las_t;

__device__ __forceinline__ void fma_s4(float4& a, const float4 w, const float v) {
    a.x = fmaf(w.x, v, a.x); a.y = fmaf(w.y, v, a.y);
    a.z = fmaf(w.z, v, a.z); a.w = fmaf(w.w, v, a.w);
}
__device__ __forceinline__ void fma_44(float4& a, const float4 w, const float4 v) {
    a.x = fmaf(w.x, v.x, a.x); a.y = fmaf(w.y, v.y, a.y);
    a.z = fmaf(w.z, v.z, a.z); a.w = fmaf(w.w, v.w, a.w);
}

// Stage one 16 KB chunk: 64 rows of 256 B (16 k x 4 h), row stride = MODES f4.
// Wave w loads rows [16w,16w+16) with 4 global_load_lds_dwordx4 (1 KB each).
__device__ __forceinline__ void stage_chunk(const float4* gbase, float4* lbuf,
                                            int wid, int lane) {
    const int sub = lane >> 4;
    const int col = lane & 15;
#pragma unroll
    for (int j = 0; j < 4; ++j) {
        const int row0 = wid * 16 + j * 4;                       // wave-uniform
        const float4* src = gbase + (size_t)(row0 + sub) * MODES + col;
        float4* dst = lbuf + row0 * KT;                          // wave-uniform
        __builtin_amdgcn_global_load_lds((gas_t)src, (las_t)dst, 16, 0, 0);
    }
}

__global__ __launch_bounds__(256, 2) void diag_lr_fused(
    const float*  __restrict__ x,
    const float4* __restrict__ Uin,
    const float4* __restrict__ Mw,
    const float4* __restrict__ Uout,
    float*        __restrict__ out)
{
    __shared__ float4 lds[4][CF4];   // 64 KB ring

    const int t    = threadIdx.x;
    const int kk   = t & 15;
    const int bs   = t >> 4;         // 0..15
    const int lane = t & 63;
    const int wid  = t >> 6;
    const int k0   = blockIdx.x * KT;
    const int k    = k0 + kk;

    const float4* UinB = Uin  + k0;
    const float4* MB   = Mw   + k0;
    const float4* UoB  = Uout + k0;
    const float*  xp0 = x + (size_t)bs        * (IN_CH * MODES) + k;
    const float*  xp1 = x + (size_t)(bs + 16) * (IN_CH * MODES) + k;
    float*        op0 = out + (size_t)bs        * (OUT_CH * MODES) + k;
    float*        op1 = out + (size_t)(bs + 16) * (OUT_CH * MODES) + k;

    // chunk index -> global base (c is compile-time after unroll)
    auto chunk_ptr = [&](int c) -> const float4* {
        return (c < 8)  ? (UinB + (size_t)c * CROWS * MODES)
             : (c == 8) ? MB
                        : (UoB + (size_t)(c - 9) * CROWS * MODES);
    };

    // ---- prologue: x(0); stage chunks 0,1 ----
    float xa[2][2][8];               // [phase&1][b-half][ii], all static indices
#pragma unroll
    for (int ii = 0; ii < 8; ++ii) {
        xa[0][0][ii] = xp0[ii * MODES];
        xa[0][1][ii] = xp1[ii * MODES];
    }
    stage_chunk(chunk_ptr(0), &lds[0][0], wid, lane);
    stage_chunk(chunk_ptr(1), &lds[1][0], wid, lane);

    float4 r0[RANK], r1[RANK];
#pragma unroll
    for (int r = 0; r < RANK; ++r) {
        r0[r] = make_float4(0.f, 0.f, 0.f, 0.f);
        r1[r] = make_float4(0.f, 0.f, 0.f, 0.f);
    }

    // ---- phases 0..7: U_in ----
#pragma unroll
    for (int c = 0; c < 8; ++c) {
        asm volatile("" ::: "memory");                 // pin issues inside phase
        if (c < 7) {                                   // x(c+1) -> xa[(c+1)&1]
#pragma unroll
            for (int ii = 0; ii < 8; ++ii) {
                xa[(c + 1) & 1][0][ii] = xp0[((c + 1) * 8 + ii) * MODES];
                xa[(c + 1) & 1][1][ii] = xp1[((c + 1) * 8 + ii) * MODES];
            }
        }
        stage_chunk(chunk_ptr(c + 2), &lds[(c + 2) & 3][0], wid, lane);
        if (c <= 6) asm volatile("s_waitcnt vmcnt(24)" ::: "memory");
        else        asm volatile("s_waitcnt vmcnt(8)"  ::: "memory");
        __builtin_amdgcn_s_barrier();
        asm volatile("" ::: "memory");
        const float4* Lb = &lds[c & 3][0];
#pragma unroll
        for (int ii = 0; ii < 8; ++ii) {
            const float xv0 = xa[c & 1][0][ii];
            const float xv1 = xa[c & 1][1][ii];
#pragma unroll
            for (int r = 0; r < RANK; ++r) {
                const float4 w = Lb[(ii * 8 + r) * KT + kk];
                fma_s4(r0[r], w, xv0);
                fma_s4(r1[r], w, xv1);
            }
        }
    }

    // ---- phase 8: M (lds[0]) ----
    float4 s0[RANK], s1[RANK];
#pragma unroll
    for (int s = 0; s < RANK; ++s) {
        s0[s] = make_float4(0.f, 0.f, 0.f, 0.f);
        s1[s] = make_float4(0.f, 0.f, 0.f, 0.f);
    }
    {
        asm volatile("" ::: "memory");
        stage_chunk(chunk_ptr(10), &lds[10 & 3][0], wid, lane);
        asm volatile("s_waitcnt vmcnt(8)" ::: "memory");
        __builtin_amdgcn_s_barrier();
        asm volatile("" ::: "memory");
        const float4* Lb = &lds[8 & 3][0];
#pragma unroll
        for (int r = 0; r < RANK; ++r)
#pragma unroll
            for (int s = 0; s < RANK; ++s) {
                const float4 w = Lb[(r * 8 + s) * KT + kk];
                fma_44(s0[s], w, r0[r]);
                fma_44(s1[s], w, r1[r]);
            }
    }

    // ---- phases 9..16: U_out ----
#pragma unroll
    for (int c = 9; c < 17; ++c) {
        asm volatile("" ::: "memory");
        if (c + 2 <= 16)
            stage_chunk(chunk_ptr(c + 2), &lds[(c + 2) & 3][0], wid, lane);
        asm volatile("s_waitcnt vmcnt(8)" ::: "memory");
        __builtin_amdgcn_s_barrier();
        asm volatile("" ::: "memory");
        const float4* Lb = &lds[c & 3][0];
        const int oc = c - 9;
#pragma unroll
        for (int oo = 0; oo < 8; ++oo) {
            float4 a0 = make_float4(0.f, 0.f, 0.f, 0.f);
            float4 a1 = make_float4(0.f, 0.f, 0.f, 0.f);
#pragma unroll
            for (int s = 0; s < RANK; ++s) {
                const float4 w = Lb[(oo * 8 + s) * KT + kk];
                fma_44(a0, w, s0[s]);
                fma_44(a1, w, s1[s]);
            }
            op0[(oc * 8 + oo) * MODES] = (a0.x + a0.y) + (a0.z + a0.w);
            op1[(oc * 8 + oo) * MODES] = (a1.x + a1.y) + (a1.z + a1.w);
        }
    }
}

extern "C" void kernel_launch(void* const* d_in, const int* in_sizes, int n_in,
                              void* d_out, int out_size, void* d_ws, size_t ws_size,
                              hipStream_t stream) {
    const float*  x    = (const float*)d_in[0];
    const float4* Uin  = (const float4*)d_in[1];
    const float4* Mw   = (const float4*)d_in[2];
    const float4* Uout = (const float4*)d_in[3];
    float* out = (float*)d_out;

    dim3 grid(512), block(256);
    hipLaunchKernelGGL(diag_lr_fused, grid, block, 0, stream, x, Uin, Mw, Uout, out);
}

// Round 5
// 74.067 us; speedup vs baseline: 1.1234x; 1.1234x over previous
//
#include <hip/hip_runtime.h>

// x     [B=32, I=64, K=8192]        f32
// U_in  [I=64, R=8,  K=8192, H=4]   f32  -> float4 per (i,r,k)
// M     [R=8,  S=8,  K=8192, H=4]   f32
// U_out [O=64, S=8,  K=8192, H=4]   f32
// out   [B=32, O=64, K=8192]        f32
//
// Block = 512 threads = 16 kk x 32 b (1 b/thread), grid = 512 (1 block/k-tile).
// -> 2 blocks/CU, 16 waves/CU (double rounds 3-4), x read exactly once.
// 17 weight chunks ([64 rows][16 kk][4 h] = 16 KB) through an R=4 LDS ring,
// staged 2 phases ahead via global_load_lds (post-barrier issue: race-free at
// D <= R-1), ONE barrier/phase, counted vmcnt per phase (never 0 mid-loop).
// Per-wave vmcnt units: stage chunk = 2 instrs, x chunk = 8, stores = 8.

static constexpr int IN_CH  = 64;
static constexpr int OUT_CH = 64;
static constexpr int RANK   = 8;
static constexpr int MODES  = 8192;
static constexpr int KT     = 16;            // k per block
static constexpr int CROWS  = 64;            // rows per chunk
static constexpr int CF4    = CROWS * KT;    // 1024 float4 = 16 KB per chunk

typedef const __attribute__((address_space(1))) void* gas_t;
typedef __attribute__((address_space(3))) void* las_t;

#define FENCE asm volatile("" ::: "memory")

__device__ __forceinline__ void fma_s4(float4& a, const float4 w, const float v) {
    a.x = fmaf(w.x, v, a.x); a.y = fmaf(w.y, v, a.y);
    a.z = fmaf(w.z, v, a.z); a.w = fmaf(w.w, v, a.w);
}
__device__ __forceinline__ void fma_44(float4& a, const float4 w, const float4 v) {
    a.x = fmaf(w.x, v.x, a.x); a.y = fmaf(w.y, v.y, a.y);
    a.z = fmaf(w.z, v.z, a.z); a.w = fmaf(w.w, v.w, a.w);
}

// 8-wave staging: wave w loads rows [8w, 8w+8) of a [64 rows][16 kk] float4
// chunk with 2 global_load_lds_dwordx4 (1 KB each; wave-uniform LDS base).
__device__ __forceinline__ void stage_chunk8(const float4* gbase, float4* lbuf,
                                             int wid, int lane) {
    const int sub = lane >> 4;       // 0..3 row within quad
    const int col = lane & 15;       // 0..15 kk
#pragma unroll
    for (int j = 0; j < 2; ++j) {
        const int row0 = wid * 8 + j * 4;                        // wave-uniform
        const float4* src = gbase + (size_t)(row0 + sub) * MODES + col;
        float4* dst = lbuf + row0 * KT;                          // wave-uniform
        __builtin_amdgcn_global_load_lds((gas_t)src, (las_t)dst, 16, 0, 0);
    }
}

__global__ __launch_bounds__(512, 4) void diag_lr_fused(
    const float*  __restrict__ x,
    const float4* __restrict__ Uin,
    const float4* __restrict__ Mw,
    const float4* __restrict__ Uout,
    float*        __restrict__ out)
{
    __shared__ float4 lds[4][CF4];   // 64 KB ring

    const int t    = threadIdx.x;
    const int kk   = t & 15;
    const int b    = t >> 4;         // 0..31 (one b per thread)
    const int lane = t & 63;
    const int wid  = t >> 6;         // 0..7
    const int k0   = blockIdx.x * KT;
    const int k    = k0 + kk;

    const float4* UinB = Uin  + k0;  // row p -> + p*MODES
    const float4* MB   = Mw   + k0;
    const float4* UoB  = Uout + k0;
    const float*  xp = x   + (size_t)b * (IN_CH  * MODES) + k;
    float*        op = out + (size_t)b * (OUT_CH * MODES) + k;

    // chunk id -> global base (folds to constants after unroll)
#define CHUNK_PTR(cc) ((cc) < 8 ? (UinB + (size_t)(cc) * CROWS * MODES) \
                     : (cc) == 8 ? MB \
                     : (UoB + (size_t)((cc) - 9) * CROWS * MODES))

    float xa[2][8];                  // x double buffer, static indices only

    // ---- prologue: queue order [s0(2), x0(8), s1(2)] ----
    stage_chunk8(CHUNK_PTR(0), &lds[0][0], wid, lane);
    FENCE;
#pragma unroll
    for (int ii = 0; ii < 8; ++ii) xa[0][ii] = xp[ii * MODES];
    FENCE;
    stage_chunk8(CHUNK_PTR(1), &lds[1][0], wid, lane);
    FENCE;

    float4 racc[RANK];
#pragma unroll
    for (int r = 0; r < RANK; ++r) racc[r] = make_float4(0.f, 0.f, 0.f, 0.f);

    // ---- phases 0..7: U_in ----
#pragma unroll
    for (int c = 0; c < 8; ++c) {
        asm volatile("s_waitcnt vmcnt(2)" ::: "memory");  // s(c), x(c) landed
        __builtin_amdgcn_s_barrier();
        FENCE;
        if (c < 7) {                                      // x(c+1) first,
#pragma unroll
            for (int ii = 0; ii < 8; ++ii)
                xa[(c + 1) & 1][ii] = xp[((c + 1) * 8 + ii) * MODES];
            FENCE;
        }
        stage_chunk8(CHUNK_PTR(c + 2), &lds[(c + 2) & 3][0], wid, lane); // then stage
        FENCE;
        const float4* Lb = &lds[c & 3][0];
#pragma unroll
        for (int ii = 0; ii < 8; ++ii) {
            const float xv = xa[c & 1][ii];
#pragma unroll
            for (int r = 0; r < RANK; ++r)
                fma_s4(racc[r], Lb[(ii * 8 + r) * KT + kk], xv);
        }
        FENCE;
    }

    // ---- phase 8: M (lds[0]) ----
    float4 sacc[RANK];
#pragma unroll
    for (int s = 0; s < RANK; ++s) sacc[s] = make_float4(0.f, 0.f, 0.f, 0.f);
    {
        asm volatile("s_waitcnt vmcnt(2)" ::: "memory");  // s8 landed, keep s9
        __builtin_amdgcn_s_barrier();
        FENCE;
        stage_chunk8(CHUNK_PTR(10), &lds[10 & 3][0], wid, lane);
        FENCE;
        const float4* Lb = &lds[8 & 3][0];
#pragma unroll
        for (int r = 0; r < RANK; ++r)
#pragma unroll
            for (int s = 0; s < RANK; ++s)
                fma_44(sacc[s], Lb[(r * 8 + s) * KT + kk], racc[r]);
        FENCE;
    }

    // ---- phases 9..16: U_out ----
#pragma unroll
    for (int c = 9; c < 17; ++c) {
        // queue at wait (instr units): ph9 [s9,s10]->keep 2; ph10 [s10,s11,st9]
        // ->keep 10; ph11-15 [s(c),st(c-2),s(c+1),st(c-1)]->keep 18;
        // ph16 [st13,s16,st14,st15]->keep 16.
        if      (c == 9)  asm volatile("s_waitcnt vmcnt(2)"  ::: "memory");
        else if (c == 10) asm volatile("s_waitcnt vmcnt(10)" ::: "memory");
        else if (c == 16) asm volatile("s_waitcnt vmcnt(16)" ::: "memory");
        else              asm volatile("s_waitcnt vmcnt(18)" ::: "memory");
        __builtin_amdgcn_s_barrier();
        FENCE;
        if (c + 2 <= 16) {
            stage_chunk8(CHUNK_PTR(c + 2), &lds[(c + 2) & 3][0], wid, lane);
            FENCE;
        }
        const float4* Lb = &lds[c & 3][0];
        const int oc = c - 9;
#pragma unroll
        for (int oo = 0; oo < 8; ++oo) {
            float4 a = make_float4(0.f, 0.f, 0.f, 0.f);
#pragma unroll
            for (int s = 0; s < RANK; ++s)
                fma_44(a, Lb[(oo * 8 + s) * KT + kk], sacc[s]);
            op[(oc * 8 + oo) * MODES] = (a.x + a.y) + (a.z + a.w);
        }
        FENCE;
    }
#undef CHUNK_PTR
}

extern "C" void kernel_launch(void* const* d_in, const int* in_sizes, int n_in,
                              void* d_out, int out_size, void* d_ws, size_t ws_size,
                              hipStream_t stream) {
    const float*  x    = (const float*)d_in[0];
    const float4* Uin  = (const float4*)d_in[1];
    const float4* Mw   = (const float4*)d_in[2];
    const float4* Uout = (const float4*)d_in[3];
    float* out = (float*)d_out;

    dim3 grid(512), block(512);
    hipLaunchKernelGGL(diag_lr_fused, grid, block, 0, stream, x, Uin, Mw, Uout, out);
}